// Round 1
// baseline (1446.390 us; speedup 1.0000x reference)
//
#include <hip/hip_runtime.h>

typedef _Float16 f16;
typedef _Float16 f16x4 __attribute__((ext_vector_type(4)));
typedef _Float16 f16x8 __attribute__((ext_vector_type(8)));
typedef float f32x4 __attribute__((ext_vector_type(4)));

#define TK 4096      // tokens
#define CD 1024      // C
#define HD 2736      // H
#define HP 2816      // H padded to 22*128
#define MT 104       // max M tiles: sum ceil(cnt_e/128) <= 72, + 32 shared
#define RC 13312     // MT*128 slot rows
#define BKP 40       // LDS row length (f16) = 32 + 8 pad, 80B = 16B-aligned

// ---- workspace layout (bytes) ----
static constexpr size_t WS_XB = 0;                         // f16 x  (8.4 MB)
static constexpr size_t WS_H  = WS_XB + (size_t)TK*CD*2;   // f16 h  (75 MB)
static constexpr size_t WS_CT = WS_H + (size_t)RC*HP*2;    // control block
static constexpr size_t CT_STOK = 0;                       // int[RC]
static constexpr size_t CT_SW   = CT_STOK + (size_t)RC*4;  // float[RC]
static constexpr size_t CT_TI   = CT_SW   + (size_t)RC*4;  // int[TK*2]
static constexpr size_t CT_TW   = CT_TI   + (size_t)TK*2*4;// float[TK*2]
static constexpr size_t CT_CNT  = CT_TW   + (size_t)TK*2*4;// int[8]
static constexpr size_t CT_PS   = CT_CNT  + 32;            // float[8]
static constexpr size_t CT_CUR  = CT_PS   + 32;            // int[8]
static constexpr size_t CT_OFF  = CT_CUR  + 32;            // int[10]
static constexpr size_t CT_SIZE = CT_OFF  + 64;

// ---------------- x -> fp16 ----------------
__global__ void k_xb(const float* __restrict__ x, f16* __restrict__ xb) {
    int i = (blockIdx.x * 256 + threadIdx.x) * 4;
    float4 v = *(const float4*)(x + i);
    f16x4 o = { (f16)v.x, (f16)v.y, (f16)v.z, (f16)v.w };
    *(f16x4*)(xb + i) = o;
}

// ---------------- router (fp32) ----------------
// one wave per token; 4 tokens per 256-thread block
__global__ void k_router(const float* __restrict__ x, const float* __restrict__ rw,
                         int* __restrict__ topi, float* __restrict__ topw,
                         int* __restrict__ cnt, float* __restrict__ psum) {
    __shared__ float pl[8];
    int tid = threadIdx.x;
    if (tid < 8) pl[tid] = 0.f;
    __syncthreads();
    int wave = tid >> 6, lane = tid & 63;
    int t = blockIdx.x * 4 + wave;
    float acc[8];
    #pragma unroll
    for (int e = 0; e < 8; e++) acc[e] = 0.f;
    const float* xr = x + (size_t)t * CD;
    for (int i = 0; i < CD / 64; i++) {
        int c = lane + i * 64;
        float xv = xr[c];
        const float* wr = rw + c * 8;
        #pragma unroll
        for (int e = 0; e < 8; e++) acc[e] = fmaf(xv, wr[e], acc[e]);
    }
    #pragma unroll
    for (int e = 0; e < 8; e++) {
        #pragma unroll
        for (int off = 32; off; off >>= 1) acc[e] += __shfl_xor(acc[e], off);
    }
    if (lane == 0) {
        float v1 = -1e30f; int i1 = 0;
        #pragma unroll
        for (int e = 0; e < 8; e++) if (acc[e] > v1) { v1 = acc[e]; i1 = e; }
        float v2 = -1e30f; int i2 = (i1 == 0) ? 1 : 0;
        #pragma unroll
        for (int e = 0; e < 8; e++) if (e != i1 && acc[e] > v2) { v2 = acc[e]; i2 = e; }
        float b = expf(v2 - v1);
        float w1 = 1.f / (1.f + b);
        topi[t*2] = i1; topi[t*2+1] = i2;
        topw[t*2] = w1; topw[t*2+1] = b * w1;
        atomicAdd(&cnt[i1], 1);
        atomicAdd(&cnt[i2], 1);
        // full softmax for aux loss p
        float m = acc[0];
        #pragma unroll
        for (int e = 1; e < 8; e++) m = fmaxf(m, acc[e]);
        float pe[8]; float s = 0.f;
        #pragma unroll
        for (int e = 0; e < 8; e++) { pe[e] = expf(acc[e] - m); s += pe[e]; }
        float inv = 1.f / s;
        #pragma unroll
        for (int e = 0; e < 8; e++) atomicAdd(&pl[e], pe[e] * inv);
    }
    __syncthreads();
    if (tid < 8) atomicAdd(&psum[tid], pl[tid]);
}

// ---------------- prefix: 128-aligned expert offsets ----------------
__global__ void k_prefix(const int* __restrict__ cnt, int* __restrict__ cur,
                         int* __restrict__ offs) {
    if (threadIdx.x == 0 && blockIdx.x == 0) {
        int off = 0;
        for (int e = 0; e < 8; e++) {
            offs[e] = off; cur[e] = off;
            off += (cnt[e] + 127) & ~127;
        }
        offs[8] = off;   // shared-expert base (4096 rows, already 128-aligned)
        offs[9] = RC;    // sentinel
    }
}

// ---------------- scatter tokens into slots ----------------
__global__ void k_scatter(const int* __restrict__ topi, const float* __restrict__ topw,
                          int* __restrict__ cur, const int* __restrict__ offs,
                          int* __restrict__ stok, float* __restrict__ sw) {
    int t = blockIdx.x * 256 + threadIdx.x;
    if (t >= TK) return;
    #pragma unroll
    for (int s = 0; s < 2; s++) {
        int e = topi[t*2 + s];
        int pos = atomicAdd(&cur[e], 1);
        stok[pos] = t;
        sw[pos] = topw[t*2 + s];
    }
    int base = offs[8];
    stok[base + t] = t;
    sw[base + t] = 1.0f;
}

// ---------------- ffn1: fused gate+up GEMM + SwiGLU -> h (f16) ----------------
__global__ __launch_bounds__(256, 2) void k_ffn1(
    const f16* __restrict__ xb, const float* __restrict__ wg,
    const float* __restrict__ wu, const float* __restrict__ sg,
    const float* __restrict__ su, const int* __restrict__ offs,
    const int* __restrict__ cnt, const int* __restrict__ stok,
    f16* __restrict__ hbuf)
{
    __shared__ f16 As[128][BKP];
    __shared__ f16 Bg[128][BKP];
    __shared__ f16 Bu[128][BKP];

    const int m0 = blockIdx.x * 128;
    const int n0 = blockIdx.y * 128;
    int g = 0;
    while (g < 8 && m0 >= offs[g+1]) g++;
    if (m0 >= offs[8] + TK) return;                       // fully unused tail tiles
    if (g < 8 && (m0 - offs[g]) >= cnt[g]) return;        // all-padding expert tiles

    const float* __restrict__ Wg = (g < 8) ? wg + (size_t)g * CD * HD : sg;
    const float* __restrict__ Wu = (g < 8) ? wu + (size_t)g * CD * HD : su;

    const int tid  = threadIdx.x;
    const int arow = tid >> 2;
    const int acol = (tid & 3) * 8;
    const f16* ap0 = xb + (size_t)stok[m0 + arow]      * CD + acol;
    const f16* ap1 = xb + (size_t)stok[m0 + arow + 64] * CD + acol;

    const int bk = tid >> 4;           // 0..15 (k within tile)
    const int bn = (tid & 15) * 8;     // 0..120 (n within tile)
    const bool full = (n0 + 128 <= HD);

    f32x4 accg[4][4], accu[4][4];
    #pragma unroll
    for (int i = 0; i < 4; i++)
        #pragma unroll
        for (int j = 0; j < 4; j++)
            #pragma unroll
            for (int r = 0; r < 4; r++) { accg[i][j][r] = 0.f; accu[i][j][r] = 0.f; }

    const int lane = tid & 63;
    const int wv = tid >> 6;
    const int wm = (wv >> 1) * 64;
    const int wn = (wv & 1) * 64;
    const int fm = lane & 15;
    const int fq = lane >> 4;

    for (int k0 = 0; k0 < CD; k0 += 32) {
        *(uint4*)&As[arow][acol]      = *(const uint4*)(ap0 + k0);
        *(uint4*)&As[arow + 64][acol] = *(const uint4*)(ap1 + k0);
        #pragma unroll
        for (int p = 0; p < 2; p++) {
            const int kk = bk + p * 16;
            const size_t gb = (size_t)(k0 + kk) * HD + n0 + bn;
            if (full) {
                float4 g0 = *(const float4*)(Wg + gb);
                float4 g1 = *(const float4*)(Wg + gb + 4);
                float4 u0 = *(const float4*)(Wu + gb);
                float4 u1 = *(const float4*)(Wu + gb + 4);
                Bg[bn+0][kk] = (f16)g0.x; Bg[bn+1][kk] = (f16)g0.y;
                Bg[bn+2][kk] = (f16)g0.z; Bg[bn+3][kk] = (f16)g0.w;
                Bg[bn+4][kk] = (f16)g1.x; Bg[bn+5][kk] = (f16)g1.y;
                Bg[bn+6][kk] = (f16)g1.z; Bg[bn+7][kk] = (f16)g1.w;
                Bu[bn+0][kk] = (f16)u0.x; Bu[bn+1][kk] = (f16)u0.y;
                Bu[bn+2][kk] = (f16)u0.z; Bu[bn+3][kk] = (f16)u0.w;
                Bu[bn+4][kk] = (f16)u1.x; Bu[bn+5][kk] = (f16)u1.y;
                Bu[bn+6][kk] = (f16)u1.z; Bu[bn+7][kk] = (f16)u1.w;
            } else {
                #pragma unroll
                for (int j = 0; j < 8; j++) {
                    int n = n0 + bn + j;
                    float vg = 0.f, vu = 0.f;
                    if (n < HD) {
                        vg = Wg[(size_t)(k0 + kk) * HD + n];
                        vu = Wu[(size_t)(k0 + kk) * HD + n];
                    }
                    Bg[bn+j][kk] = (f16)vg;
                    Bu[bn+j][kk] = (f16)vu;
                }
            }
        }
        __syncthreads();
        f16x8 af[4];
        #pragma unroll
        for (int mi = 0; mi < 4; mi++)
            af[mi] = *(const f16x8*)&As[wm + mi*16 + fm][fq*8];
        #pragma unroll
        for (int ni = 0; ni < 4; ni++) {
            f16x8 bgf = *(const f16x8*)&Bg[wn + ni*16 + fm][fq*8];
            f16x8 buf = *(const f16x8*)&Bu[wn + ni*16 + fm][fq*8];
            #pragma unroll
            for (int mi = 0; mi < 4; mi++) {
                accg[mi][ni] = __builtin_amdgcn_mfma_f32_16x16x32_f16(af[mi], bgf, accg[mi][ni], 0, 0, 0);
                accu[mi][ni] = __builtin_amdgcn_mfma_f32_16x16x32_f16(af[mi], buf, accu[mi][ni], 0, 0, 0);
            }
        }
        __syncthreads();
    }

    // SwiGLU epilogue: h = silu(g) * u, f16 store (padding cols land as 0: B was 0)
    #pragma unroll
    for (int mi = 0; mi < 4; mi++) {
        #pragma unroll
        for (int ni = 0; ni < 4; ni++) {
            #pragma unroll
            for (int r = 0; r < 4; r++) {
                int row = m0 + wm + mi*16 + fq*4 + r;
                int col = n0 + wn + ni*16 + fm;
                float gv = accg[mi][ni][r];
                float uv = accu[mi][ni][r];
                float hv = gv / (1.f + __expf(-gv)) * uv;
                hbuf[(size_t)row * HP + col] = (f16)hv;
            }
        }
    }
}

// ---------------- ffn2: down GEMM + weighted scatter-add ----------------
__global__ __launch_bounds__(256, 2) void k_ffn2(
    const f16* __restrict__ hbuf, const float* __restrict__ wd,
    const float* __restrict__ sd, const int* __restrict__ offs,
    const int* __restrict__ cnt, const int* __restrict__ stok,
    const float* __restrict__ sw, float* __restrict__ out)
{
    __shared__ f16 As[128][BKP];
    __shared__ f16 Bs[128][BKP];

    const int m0 = blockIdx.x * 128;
    const int n0 = blockIdx.y * 128;
    int g = 0;
    while (g < 8 && m0 >= offs[g+1]) g++;
    if (m0 >= offs[8] + TK) return;
    if (g < 8 && (m0 - offs[g]) >= cnt[g]) return;
    const float* __restrict__ W = (g < 8) ? wd + (size_t)g * HD * CD : sd;

    const int tid  = threadIdx.x;
    const int arow = tid >> 2;
    const int acol = (tid & 3) * 8;
    const f16* ap0 = hbuf + (size_t)(m0 + arow)      * HP + acol;
    const f16* ap1 = hbuf + (size_t)(m0 + arow + 64) * HP + acol;
    const int bk = tid >> 4;
    const int bn = (tid & 15) * 8;

    f32x4 acc[4][4];
    #pragma unroll
    for (int i = 0; i < 4; i++)
        #pragma unroll
        for (int j = 0; j < 4; j++)
            #pragma unroll
            for (int r = 0; r < 4; r++) acc[i][j][r] = 0.f;

    const int lane = tid & 63;
    const int wv = tid >> 6;
    const int wm = (wv >> 1) * 64;
    const int wn = (wv & 1) * 64;
    const int fm = lane & 15;
    const int fq = lane >> 4;

    for (int k0 = 0; k0 < HP; k0 += 32) {
        *(uint4*)&As[arow][acol]      = *(const uint4*)(ap0 + k0);
        *(uint4*)&As[arow + 64][acol] = *(const uint4*)(ap1 + k0);
        #pragma unroll
        for (int p = 0; p < 2; p++) {
            const int kk = bk + p * 16;
            const int kg = k0 + kk;
            float4 v0 = {0.f,0.f,0.f,0.f}, v1 = {0.f,0.f,0.f,0.f};
            if (kg < HD) {
                v0 = *(const float4*)(W + (size_t)kg * CD + n0 + bn);
                v1 = *(const float4*)(W + (size_t)kg * CD + n0 + bn + 4);
            }
            Bs[bn+0][kk] = (f16)v0.x; Bs[bn+1][kk] = (f16)v0.y;
            Bs[bn+2][kk] = (f16)v0.z; Bs[bn+3][kk] = (f16)v0.w;
            Bs[bn+4][kk] = (f16)v1.x; Bs[bn+5][kk] = (f16)v1.y;
            Bs[bn+6][kk] = (f16)v1.z; Bs[bn+7][kk] = (f16)v1.w;
        }
        __syncthreads();
        f16x8 af[4];
        #pragma unroll
        for (int mi = 0; mi < 4; mi++)
            af[mi] = *(const f16x8*)&As[wm + mi*16 + fm][fq*8];
        #pragma unroll
        for (int ni = 0; ni < 4; ni++) {
            f16x8 bfr = *(const f16x8*)&Bs[wn + ni*16 + fm][fq*8];
            #pragma unroll
            for (int mi = 0; mi < 4; mi++)
                acc[mi][ni] = __builtin_amdgcn_mfma_f32_16x16x32_f16(af[mi], bfr, acc[mi][ni], 0, 0, 0);
        }
        __syncthreads();
    }

    #pragma unroll
    for (int mi = 0; mi < 4; mi++) {
        #pragma unroll
        for (int r = 0; r < 4; r++) {
            int row = m0 + wm + mi*16 + fq*4 + r;
            int tok = stok[row];
            float w = sw[row];
            if (w != 0.f) {
                #pragma unroll
                for (int ni = 0; ni < 4; ni++) {
                    int col = n0 + wn + ni*16 + fm;
                    atomicAdd(&out[(size_t)tok * CD + col], w * acc[mi][ni][r]);
                }
            }
        }
    }
}

// ---------------- aux loss ----------------
__global__ void k_aux(const int* __restrict__ cnt, const float* __restrict__ psum,
                      float* __restrict__ out_aux) {
    if (threadIdx.x == 0 && blockIdx.x == 0) {
        float a = 0.f;
        for (int e = 0; e < 8; e++) {
            float f = (float)cnt[e] / ((float)TK * 2.f);
            float p = psum[e] / (float)TK;
            a += f * p;
        }
        out_aux[0] = 8.f * a;
    }
}

extern "C" void kernel_launch(void* const* d_in, const int* in_sizes, int n_in,
                              void* d_out, int out_size, void* d_ws, size_t ws_size,
                              hipStream_t stream) {
    const float* x  = (const float*)d_in[0];
    const float* rw = (const float*)d_in[1];
    const float* wg = (const float*)d_in[2];
    const float* wu = (const float*)d_in[3];
    const float* wd = (const float*)d_in[4];
    const float* sg = (const float*)d_in[5];
    const float* su = (const float*)d_in[6];
    const float* sd = (const float*)d_in[7];
    float* out = (float*)d_out;

    char* ws = (char*)d_ws;
    f16* xb    = (f16*)(ws + WS_XB);
    f16* hbuf  = (f16*)(ws + WS_H);
    char* ct   = ws + WS_CT;
    int*   stok = (int*)  (ct + CT_STOK);
    float* swt  = (float*)(ct + CT_SW);
    int*   topi = (int*)  (ct + CT_TI);
    float* topw = (float*)(ct + CT_TW);
    int*   cnt  = (int*)  (ct + CT_CNT);
    float* psum = (float*)(ct + CT_PS);
    int*   cur  = (int*)  (ct + CT_CUR);
    int*   offs = (int*)  (ct + CT_OFF);

    hipMemsetAsync(d_out, 0, (size_t)(TK * CD + 1) * 4, stream);
    hipMemsetAsync(ct, 0, CT_SIZE, stream);

    k_xb<<<dim3(TK * CD / 1024), dim3(256), 0, stream>>>(x, xb);
    k_router<<<dim3(TK / 4), dim3(256), 0, stream>>>(x, rw, topi, topw, cnt, psum);
    k_prefix<<<dim3(1), dim3(64), 0, stream>>>(cnt, cur, offs);
    k_scatter<<<dim3(TK / 256), dim3(256), 0, stream>>>(topi, topw, cur, offs, stok, swt);
    k_ffn1<<<dim3(MT, HP / 128), dim3(256), 0, stream>>>(xb, wg, wu, sg, su, offs, cnt, stok, hbuf);
    k_ffn2<<<dim3(MT, CD / 128), dim3(256), 0, stream>>>(hbuf, wd, sd, offs, cnt, stok, swt, out);
    k_aux<<<dim3(1), dim3(64), 0, stream>>>(cnt, psum, out + (size_t)TK * CD);
}

// Round 2
// 865.608 us; speedup vs baseline: 1.6710x; 1.6710x over previous
//
#include <hip/hip_runtime.h>

typedef _Float16 f16;
typedef _Float16 f16x4 __attribute__((ext_vector_type(4)));
typedef _Float16 f16x8 __attribute__((ext_vector_type(8)));
typedef float f32x4 __attribute__((ext_vector_type(4)));

#define TK 4096      // tokens
#define CD 1024      // C
#define HD 2736      // H
#define HP 2816      // H padded to 22*128
#define MT 104       // max M tiles: sum ceil(cnt_e/128) <= 72, + 32 shared
#define RC 13312     // MT*128 slot rows

// async global->LDS, 16B per lane, lds dest = wave-uniform base + lane*16
#define GLDS16(ldsp, gp) __builtin_amdgcn_global_load_lds( \
    (const __attribute__((address_space(1))) unsigned int*)(gp), \
    (__attribute__((address_space(3))) unsigned int*)(ldsp), 16, 0, 0)

// ---- workspace layout (bytes) ----
static constexpr size_t WS_XB  = 0;                               // f16 x (8.4 MB)
static constexpr size_t WS_H   = WS_XB  + (size_t)TK*CD*2;        // f16 h (75 MB)
static constexpr size_t WS_WGT = WS_H   + (size_t)RC*HP*2;        // f16 [8][HP][CD]
static constexpr size_t WS_WUT = WS_WGT + (size_t)8*HP*CD*2;
static constexpr size_t WS_WDT = WS_WUT + (size_t)8*HP*CD*2;      // f16 [8][CD][HP]
static constexpr size_t WS_SGT = WS_WDT + (size_t)8*CD*HP*2;      // f16 [HP][CD]
static constexpr size_t WS_SUT = WS_SGT + (size_t)HP*CD*2;
static constexpr size_t WS_SDT = WS_SUT + (size_t)HP*CD*2;        // f16 [CD][HP]
static constexpr size_t WS_CT  = WS_SDT + (size_t)CD*HP*2;        // control block
static constexpr size_t CT_STOK = 0;                         // int[RC]
static constexpr size_t CT_SW   = CT_STOK + (size_t)RC*4;    // float[RC]
static constexpr size_t CT_TI   = CT_SW   + (size_t)RC*4;    // int[TK*2]
static constexpr size_t CT_TW   = CT_TI   + (size_t)TK*2*4;  // float[TK*2]
static constexpr size_t CT_CNT  = CT_TW   + (size_t)TK*2*4;  // int[8]
static constexpr size_t CT_PS   = CT_CNT  + 32;              // float[8]
static constexpr size_t CT_CUR  = CT_PS   + 32;              // int[8]
static constexpr size_t CT_OFF  = CT_CUR  + 32;              // int[10]
static constexpr size_t CT_SIZE = CT_OFF  + 64;

// ---------------- x -> fp16 ----------------
__global__ void k_xb(const float* __restrict__ x, f16* __restrict__ xb) {
    int i = (blockIdx.x * 256 + threadIdx.x) * 4;
    float4 v = *(const float4*)(x + i);
    f16x4 o = { (f16)v.x, (f16)v.y, (f16)v.z, (f16)v.w };
    *(f16x4*)(xb + i) = o;
}

// ---------------- weight convert + transpose (fp32 [R][Cc] -> f16 [Cp][Rp], 0-pad) ----
__global__ void k_tr(const float* __restrict__ src, f16* __restrict__ dst,
                     int R, int Cc, int Rp, int Cp,
                     size_t sstride, size_t dstride) {
    __shared__ f16 t[32][33];
    src += (size_t)blockIdx.z * sstride;
    dst += (size_t)blockIdx.z * dstride;
    int c = blockIdx.x * 32 + threadIdx.x;
    #pragma unroll
    for (int j = 0; j < 4; j++) {
        int r = blockIdx.y * 32 + threadIdx.y + j * 8;
        float v = (r < R && c < Cc) ? src[(size_t)r * Cc + c] : 0.f;
        t[threadIdx.x][threadIdx.y + j * 8] = (f16)v;
    }
    __syncthreads();
    int rr = blockIdx.y * 32 + threadIdx.x;          // dst inner (k)
    #pragma unroll
    for (int j = 0; j < 4; j++) {
        int cc = blockIdx.x * 32 + threadIdx.y + j * 8;  // dst row (n)
        if (cc < Cp && rr < Rp)
            dst[(size_t)cc * Rp + rr] = t[threadIdx.y + j * 8][threadIdx.x];
    }
}

// ---------------- router (fp32) ----------------
__global__ void k_router(const float* __restrict__ x, const float* __restrict__ rw,
                         int* __restrict__ topi, float* __restrict__ topw,
                         int* __restrict__ cnt, float* __restrict__ psum) {
    __shared__ float pl[8];
    int tid = threadIdx.x;
    if (tid < 8) pl[tid] = 0.f;
    __syncthreads();
    int wave = tid >> 6, lane = tid & 63;
    int t = blockIdx.x * 4 + wave;
    float acc[8];
    #pragma unroll
    for (int e = 0; e < 8; e++) acc[e] = 0.f;
    const float* xr = x + (size_t)t * CD;
    for (int i = 0; i < CD / 64; i++) {
        int c = lane + i * 64;
        float xv = xr[c];
        const float* wr = rw + c * 8;
        #pragma unroll
        for (int e = 0; e < 8; e++) acc[e] = fmaf(xv, wr[e], acc[e]);
    }
    #pragma unroll
    for (int e = 0; e < 8; e++) {
        #pragma unroll
        for (int off = 32; off; off >>= 1) acc[e] += __shfl_xor(acc[e], off);
    }
    if (lane == 0) {
        float v1 = -1e30f; int i1 = 0;
        #pragma unroll
        for (int e = 0; e < 8; e++) if (acc[e] > v1) { v1 = acc[e]; i1 = e; }
        float v2 = -1e30f; int i2 = (i1 == 0) ? 1 : 0;
        #pragma unroll
        for (int e = 0; e < 8; e++) if (e != i1 && acc[e] > v2) { v2 = acc[e]; i2 = e; }
        float b = expf(v2 - v1);
        float w1 = 1.f / (1.f + b);
        topi[t*2] = i1; topi[t*2+1] = i2;
        topw[t*2] = w1; topw[t*2+1] = b * w1;
        atomicAdd(&cnt[i1], 1);
        atomicAdd(&cnt[i2], 1);
        float m = acc[0];
        #pragma unroll
        for (int e = 1; e < 8; e++) m = fmaxf(m, acc[e]);
        float pe[8]; float s = 0.f;
        #pragma unroll
        for (int e = 0; e < 8; e++) { pe[e] = expf(acc[e] - m); s += pe[e]; }
        float inv = 1.f / s;
        #pragma unroll
        for (int e = 0; e < 8; e++) atomicAdd(&pl[e], pe[e] * inv);
    }
    __syncthreads();
    if (tid < 8) atomicAdd(&psum[tid], pl[tid]);
}

// ---------------- prefix: 128-aligned expert offsets ----------------
__global__ void k_prefix(const int* __restrict__ cnt, int* __restrict__ cur,
                         int* __restrict__ offs) {
    if (threadIdx.x == 0 && blockIdx.x == 0) {
        int off = 0;
        for (int e = 0; e < 8; e++) {
            offs[e] = off; cur[e] = off;
            off += (cnt[e] + 127) & ~127;
        }
        offs[8] = off;
        offs[9] = RC;
    }
}

// ---------------- scatter tokens into slots ----------------
__global__ void k_scatter(const int* __restrict__ topi, const float* __restrict__ topw,
                          int* __restrict__ cur, const int* __restrict__ offs,
                          int* __restrict__ stok, float* __restrict__ sw) {
    int t = blockIdx.x * 256 + threadIdx.x;
    if (t >= TK) return;
    #pragma unroll
    for (int s = 0; s < 2; s++) {
        int e = topi[t*2 + s];
        int pos = atomicAdd(&cur[e], 1);
        stok[pos] = t;
        sw[pos] = topw[t*2 + s];
    }
    int base = offs[8];
    stok[base + t] = t;
    sw[base + t] = 1.0f;
}

// ---------------- ffn1: fused gate+up GEMM + SwiGLU -> h (f16) ----------------
// m97 structure: global_load_lds dwordx4 staging, unpadded [128][32] LDS tiles
__global__ __launch_bounds__(256, 2) void k_ffn1(
    const f16* __restrict__ xb, const f16* __restrict__ wgt,
    const f16* __restrict__ wut, const f16* __restrict__ sgt,
    const f16* __restrict__ sut, const int* __restrict__ offs,
    const int* __restrict__ cnt, const int* __restrict__ stok,
    f16* __restrict__ hbuf)
{
    __shared__ f16 As[128*32];
    __shared__ f16 Bg[128*32];
    __shared__ f16 Bu[128*32];

    const int m0 = blockIdx.x * 128;
    const int n0 = blockIdx.y * 128;
    int g = 0;
    while (g < 8 && m0 >= offs[g+1]) g++;
    if (m0 >= offs[8] + TK) return;
    if (g < 8 && (m0 - offs[g]) >= cnt[g]) return;

    const f16* __restrict__ Wg = (g < 8) ? wgt + (size_t)g * HP * CD : sgt;
    const f16* __restrict__ Wu = (g < 8) ? wut + (size_t)g * HP * CD : sut;

    const int tid = threadIdx.x;
    const int lane = tid & 63;
    const int w = tid >> 6;
    // staging: lane covers row r0 = w*32 + lane/4 (+16 for 2nd chunk), 8 f16 at (lane&3)*8
    const int r0  = w * 32 + (lane >> 2);
    const int kof = (lane & 3) * 8;
    const f16* pa0 = xb + (size_t)stok[m0 + r0]      * CD + kof;
    const f16* pa1 = xb + (size_t)stok[m0 + r0 + 16] * CD + kof;
    const f16* pg0 = Wg + (size_t)(n0 + r0)      * CD + kof;
    const f16* pg1 = Wg + (size_t)(n0 + r0 + 16) * CD + kof;
    const f16* pu0 = Wu + (size_t)(n0 + r0)      * CD + kof;
    const f16* pu1 = Wu + (size_t)(n0 + r0 + 16) * CD + kof;
    f16* const lA = As + w * 1024;   // wave chunk base (1024 f16 = 2 KB... 1024*2B; chunk=512 f16)
    f16* const lG = Bg + w * 1024;
    f16* const lU = Bu + w * 1024;

    f32x4 accg[4][4], accu[4][4];
    #pragma unroll
    for (int i = 0; i < 4; i++)
        #pragma unroll
        for (int j = 0; j < 4; j++)
            #pragma unroll
            for (int r = 0; r < 4; r++) { accg[i][j][r] = 0.f; accu[i][j][r] = 0.f; }

    const int wm = (w >> 1) * 64;
    const int wn = (w & 1) * 64;
    const int fm = lane & 15;
    const int fq = lane >> 4;

    for (int k0 = 0; k0 < CD; k0 += 32) {
        GLDS16(lA,       pa0 + k0);
        GLDS16(lA + 512, pa1 + k0);
        GLDS16(lG,       pg0 + k0);
        GLDS16(lG + 512, pg1 + k0);
        GLDS16(lU,       pu0 + k0);
        GLDS16(lU + 512, pu1 + k0);
        __syncthreads();
        f16x8 af[4];
        #pragma unroll
        for (int mi = 0; mi < 4; mi++)
            af[mi] = *(const f16x8*)&As[(wm + mi*16 + fm) * 32 + fq * 8];
        #pragma unroll
        for (int ni = 0; ni < 4; ni++) {
            f16x8 bgf = *(const f16x8*)&Bg[(wn + ni*16 + fm) * 32 + fq * 8];
            f16x8 buf = *(const f16x8*)&Bu[(wn + ni*16 + fm) * 32 + fq * 8];
            #pragma unroll
            for (int mi = 0; mi < 4; mi++) {
                accg[mi][ni] = __builtin_amdgcn_mfma_f32_16x16x32_f16(af[mi], bgf, accg[mi][ni], 0, 0, 0);
                accu[mi][ni] = __builtin_amdgcn_mfma_f32_16x16x32_f16(af[mi], buf, accu[mi][ni], 0, 0, 0);
            }
        }
        __syncthreads();
    }

    // SwiGLU epilogue (pad cols n>=HD: B was 0 -> h=0)
    #pragma unroll
    for (int mi = 0; mi < 4; mi++) {
        #pragma unroll
        for (int ni = 0; ni < 4; ni++) {
            #pragma unroll
            for (int r = 0; r < 4; r++) {
                int row = m0 + wm + mi*16 + fq*4 + r;
                int col = n0 + wn + ni*16 + fm;
                float gv = accg[mi][ni][r];
                float uv = accu[mi][ni][r];
                float hv = gv / (1.f + __expf(-gv)) * uv;
                hbuf[(size_t)row * HP + col] = (f16)hv;
            }
        }
    }
}

// ---------------- ffn2: down GEMM + weighted scatter-add ----------------
__global__ __launch_bounds__(256, 2) void k_ffn2(
    const f16* __restrict__ hbuf, const f16* __restrict__ wdt,
    const f16* __restrict__ sdt, const int* __restrict__ offs,
    const int* __restrict__ cnt, const int* __restrict__ stok,
    const float* __restrict__ sw, float* __restrict__ out)
{
    __shared__ f16 As[128*32];
    __shared__ f16 Bs[128*32];

    const int m0 = blockIdx.x * 128;
    const int n0 = blockIdx.y * 128;
    int g = 0;
    while (g < 8 && m0 >= offs[g+1]) g++;
    if (m0 >= offs[8] + TK) return;
    if (g < 8 && (m0 - offs[g]) >= cnt[g]) return;
    const f16* __restrict__ W = (g < 8) ? wdt + (size_t)g * CD * HP : sdt;

    const int tid = threadIdx.x;
    const int lane = tid & 63;
    const int w = tid >> 6;
    const int r0  = w * 32 + (lane >> 2);
    const int kof = (lane & 3) * 8;
    const f16* pa0 = hbuf + (size_t)(m0 + r0)      * HP + kof;
    const f16* pa1 = hbuf + (size_t)(m0 + r0 + 16) * HP + kof;
    const f16* pb0 = W + (size_t)(n0 + r0)      * HP + kof;
    const f16* pb1 = W + (size_t)(n0 + r0 + 16) * HP + kof;
    f16* const lA = As + w * 1024;
    f16* const lB = Bs + w * 1024;

    f32x4 acc[4][4];
    #pragma unroll
    for (int i = 0; i < 4; i++)
        #pragma unroll
        for (int j = 0; j < 4; j++)
            #pragma unroll
            for (int r = 0; r < 4; r++) acc[i][j][r] = 0.f;

    const int wm = (w >> 1) * 64;
    const int wn = (w & 1) * 64;
    const int fm = lane & 15;
    const int fq = lane >> 4;

    for (int k0 = 0; k0 < HP; k0 += 32) {
        GLDS16(lA,       pa0 + k0);
        GLDS16(lA + 512, pa1 + k0);
        GLDS16(lB,       pb0 + k0);
        GLDS16(lB + 512, pb1 + k0);
        __syncthreads();
        f16x8 af[4];
        #pragma unroll
        for (int mi = 0; mi < 4; mi++)
            af[mi] = *(const f16x8*)&As[(wm + mi*16 + fm) * 32 + fq * 8];
        #pragma unroll
        for (int ni = 0; ni < 4; ni++) {
            f16x8 bfr = *(const f16x8*)&Bs[(wn + ni*16 + fm) * 32 + fq * 8];
            #pragma unroll
            for (int mi = 0; mi < 4; mi++)
                acc[mi][ni] = __builtin_amdgcn_mfma_f32_16x16x32_f16(af[mi], bfr, acc[mi][ni], 0, 0, 0);
        }
        __syncthreads();
    }

    #pragma unroll
    for (int mi = 0; mi < 4; mi++) {
        #pragma unroll
        for (int r = 0; r < 4; r++) {
            int row = m0 + wm + mi*16 + fq*4 + r;
            int tok = stok[row];
            float wgt = sw[row];
            if (wgt != 0.f) {
                #pragma unroll
                for (int ni = 0; ni < 4; ni++) {
                    int col = n0 + wn + ni*16 + fm;
                    atomicAdd(&out[(size_t)tok * CD + col], wgt * acc[mi][ni][r]);
                }
            }
        }
    }
}

// ---------------- aux loss ----------------
__global__ void k_aux(const int* __restrict__ cnt, const float* __restrict__ psum,
                      float* __restrict__ out_aux) {
    if (threadIdx.x == 0 && blockIdx.x == 0) {
        float a = 0.f;
        for (int e = 0; e < 8; e++) {
            float f = (float)cnt[e] / ((float)TK * 2.f);
            float p = psum[e] / (float)TK;
            a += f * p;
        }
        out_aux[0] = 8.f * a;
    }
}

extern "C" void kernel_launch(void* const* d_in, const int* in_sizes, int n_in,
                              void* d_out, int out_size, void* d_ws, size_t ws_size,
                              hipStream_t stream) {
    const float* x  = (const float*)d_in[0];
    const float* rw = (const float*)d_in[1];
    const float* wg = (const float*)d_in[2];
    const float* wu = (const float*)d_in[3];
    const float* wd = (const float*)d_in[4];
    const float* sg = (const float*)d_in[5];
    const float* su = (const float*)d_in[6];
    const float* sd = (const float*)d_in[7];
    float* out = (float*)d_out;

    char* ws = (char*)d_ws;
    f16* xb   = (f16*)(ws + WS_XB);
    f16* hbuf = (f16*)(ws + WS_H);
    f16* wgt  = (f16*)(ws + WS_WGT);
    f16* wut  = (f16*)(ws + WS_WUT);
    f16* wdt  = (f16*)(ws + WS_WDT);
    f16* sgt  = (f16*)(ws + WS_SGT);
    f16* sut  = (f16*)(ws + WS_SUT);
    f16* sdt  = (f16*)(ws + WS_SDT);
    char* ct  = ws + WS_CT;
    int*   stok = (int*)  (ct + CT_STOK);
    float* swt  = (float*)(ct + CT_SW);
    int*   topi = (int*)  (ct + CT_TI);
    float* topw = (float*)(ct + CT_TW);
    int*   cnt  = (int*)  (ct + CT_CNT);
    float* psum = (float*)(ct + CT_PS);
    int*   cur  = (int*)  (ct + CT_CUR);
    int*   offs = (int*)  (ct + CT_OFF);

    hipMemsetAsync(d_out, 0, (size_t)(TK * CD + 1) * 4, stream);
    hipMemsetAsync(ct, 0, CT_SIZE, stream);

    k_xb<<<dim3(TK * CD / 1024), dim3(256), 0, stream>>>(x, xb);
    k_router<<<dim3(TK / 4), dim3(256), 0, stream>>>(x, rw, topi, topw, cnt, psum);
    k_prefix<<<dim3(1), dim3(64), 0, stream>>>(cnt, cur, offs);
    k_scatter<<<dim3(TK / 256), dim3(256), 0, stream>>>(topi, topw, cur, offs, stok, swt);

    // weight convert+transpose: [R][Cc] fp32 -> [Cp][Rp] f16 (0-padded)
    k_tr<<<dim3(HP/32, CD/32, 8), dim3(32, 8), 0, stream>>>(wg, wgt, CD, HD, CD, HP, (size_t)CD*HD, (size_t)HP*CD);
    k_tr<<<dim3(HP/32, CD/32, 8), dim3(32, 8), 0, stream>>>(wu, wut, CD, HD, CD, HP, (size_t)CD*HD, (size_t)HP*CD);
    k_tr<<<dim3(CD/32, HP/32, 8), dim3(32, 8), 0, stream>>>(wd, wdt, HD, CD, HP, CD, (size_t)HD*CD, (size_t)CD*HP);
    k_tr<<<dim3(HP/32, CD/32, 1), dim3(32, 8), 0, stream>>>(sg, sgt, CD, HD, CD, HP, 0, 0);
    k_tr<<<dim3(HP/32, CD/32, 1), dim3(32, 8), 0, stream>>>(su, sut, CD, HD, CD, HP, 0, 0);
    k_tr<<<dim3(CD/32, HP/32, 1), dim3(32, 8), 0, stream>>>(sd, sdt, HD, CD, HP, CD, 0, 0);

    k_ffn1<<<dim3(MT, HP / 128), dim3(256), 0, stream>>>(xb, wgt, wut, sgt, sut, offs, cnt, stok, hbuf);
    k_ffn2<<<dim3(MT, CD / 128), dim3(256), 0, stream>>>(hbuf, wdt, sdt, offs, cnt, stok, swt, out);
    k_aux<<<dim3(1), dim3(64), 0, stream>>>(cnt, psum, out + (size_t)TK * CD);
}

// Round 3
// 832.871 us; speedup vs baseline: 1.7366x; 1.0393x over previous
//
#include <hip/hip_runtime.h>

typedef _Float16 f16;
typedef _Float16 f16x4 __attribute__((ext_vector_type(4)));
typedef _Float16 f16x8 __attribute__((ext_vector_type(8)));
typedef float f32x4 __attribute__((ext_vector_type(4)));

#define TK 4096      // tokens
#define CD 1024      // C
#define HD 2736      // H
#define HP 2816      // H padded to 22*128
#define MT 104       // max M tiles: sum ceil(cnt_e/128) <= 72, + 32 shared
#define RC 13312     // MT*128 slot rows

// async global->LDS, 16B per lane, lds dest = wave-uniform base + lane*16
#define GLDS16(ldsp, gp) __builtin_amdgcn_global_load_lds( \
    (const __attribute__((address_space(1))) unsigned int*)(gp), \
    (__attribute__((address_space(3))) unsigned int*)(ldsp), 16, 0, 0)

// ---- workspace layout (bytes) ----
static constexpr size_t WS_XB  = 0;                               // f16 x (8.4 MB)
static constexpr size_t WS_H   = WS_XB  + (size_t)TK*CD*2;        // f16 h (75 MB)
static constexpr size_t WS_WGT = WS_H   + (size_t)RC*HP*2;        // f16 [8][HP][CD]
static constexpr size_t WS_WUT = WS_WGT + (size_t)8*HP*CD*2;
static constexpr size_t WS_WDT = WS_WUT + (size_t)8*HP*CD*2;      // f16 [8][CD][HP]
static constexpr size_t WS_SGT = WS_WDT + (size_t)8*CD*HP*2;      // f16 [HP][CD]
static constexpr size_t WS_SUT = WS_SGT + (size_t)HP*CD*2;
static constexpr size_t WS_SDT = WS_SUT + (size_t)HP*CD*2;        // f16 [CD][HP]
static constexpr size_t WS_CT  = WS_SDT + (size_t)CD*HP*2;        // control block
static constexpr size_t CT_STOK = 0;                         // int[RC]
static constexpr size_t CT_SW   = CT_STOK + (size_t)RC*4;    // float[RC]
static constexpr size_t CT_TI   = CT_SW   + (size_t)RC*4;    // int[TK*2]
static constexpr size_t CT_TW   = CT_TI   + (size_t)TK*2*4;  // float[TK*2]
static constexpr size_t CT_CNT  = CT_TW   + (size_t)TK*2*4;  // int[8]
static constexpr size_t CT_PS   = CT_CNT  + 32;              // float[8]
static constexpr size_t CT_CUR  = CT_PS   + 32;              // int[8]
static constexpr size_t CT_OFF  = CT_CUR  + 32;              // int[10]
static constexpr size_t CT_SIZE = CT_OFF  + 64;

// ---------------- x -> fp16 ----------------
__global__ void k_xb(const float* __restrict__ x, f16* __restrict__ xb) {
    int i = (blockIdx.x * 256 + threadIdx.x) * 4;
    float4 v = *(const float4*)(x + i);
    f16x4 o = { (f16)v.x, (f16)v.y, (f16)v.z, (f16)v.w };
    *(f16x4*)(xb + i) = o;
}

// ---------------- weight convert+transpose, register-only ----------------
// src fp32 [R][Cc] -> dst f16 [Cp][Rp], zero-padded. Block = 256 thr covers
// dst region 128 rows (cc) x 64 cols (rr). Each lane: 8 coalesced float4 row
// loads, register transpose, 4 f16x8 (16B) stores.
__global__ __launch_bounds__(256) void k_tr(const float* __restrict__ src, f16* __restrict__ dst,
                     int R, int Cc, int Rp, int Cp,
                     size_t sstride, size_t dstride) {
    src += (size_t)blockIdx.z * sstride;
    dst += (size_t)blockIdx.z * dstride;
    const int tid = threadIdx.x;
    const int l = tid & 63, w = tid >> 6;
    const int cc0 = blockIdx.x * 128 + w * 32 + (l >> 3) * 4;   // dst row = src col
    const int rr0 = blockIdx.y * 64 + (l & 7) * 8;              // dst col = src row
    float4 v[8];
    #pragma unroll
    for (int e = 0; e < 8; e++) {
        int gr = rr0 + e;
        if (gr < R && cc0 + 3 < Cc) {
            v[e] = *(const float4*)(src + (size_t)gr * Cc + cc0);
        } else {
            float* ve = (float*)&v[e];
            #pragma unroll
            for (int c = 0; c < 4; c++)
                ve[c] = (gr < R && cc0 + c < Cc) ? src[(size_t)gr * Cc + cc0 + c] : 0.f;
        }
    }
    #pragma unroll
    for (int c = 0; c < 4; c++) {
        const float* vp = (const float*)v;
        f16x8 o = { (f16)vp[0*4+c], (f16)vp[1*4+c], (f16)vp[2*4+c], (f16)vp[3*4+c],
                    (f16)vp[4*4+c], (f16)vp[5*4+c], (f16)vp[6*4+c], (f16)vp[7*4+c] };
        *(f16x8*)(dst + (size_t)(cc0 + c) * Rp + rr0) = o;
    }
}

// ---------------- router (fp32) ----------------
__global__ void k_router(const float* __restrict__ x, const float* __restrict__ rw,
                         int* __restrict__ topi, float* __restrict__ topw,
                         int* __restrict__ cnt, float* __restrict__ psum) {
    __shared__ float pl[8];
    int tid = threadIdx.x;
    if (tid < 8) pl[tid] = 0.f;
    __syncthreads();
    int wave = tid >> 6, lane = tid & 63;
    int t = blockIdx.x * 4 + wave;
    float acc[8];
    #pragma unroll
    for (int e = 0; e < 8; e++) acc[e] = 0.f;
    const float* xr = x + (size_t)t * CD;
    for (int i = 0; i < CD / 64; i++) {
        int c = lane + i * 64;
        float xv = xr[c];
        const float* wr = rw + c * 8;
        #pragma unroll
        for (int e = 0; e < 8; e++) acc[e] = fmaf(xv, wr[e], acc[e]);
    }
    #pragma unroll
    for (int e = 0; e < 8; e++) {
        #pragma unroll
        for (int off = 32; off; off >>= 1) acc[e] += __shfl_xor(acc[e], off);
    }
    if (lane == 0) {
        float v1 = -1e30f; int i1 = 0;
        #pragma unroll
        for (int e = 0; e < 8; e++) if (acc[e] > v1) { v1 = acc[e]; i1 = e; }
        float v2 = -1e30f; int i2 = (i1 == 0) ? 1 : 0;
        #pragma unroll
        for (int e = 0; e < 8; e++) if (e != i1 && acc[e] > v2) { v2 = acc[e]; i2 = e; }
        float b = expf(v2 - v1);
        float w1 = 1.f / (1.f + b);
        topi[t*2] = i1; topi[t*2+1] = i2;
        topw[t*2] = w1; topw[t*2+1] = b * w1;
        atomicAdd(&cnt[i1], 1);
        atomicAdd(&cnt[i2], 1);
        float m = acc[0];
        #pragma unroll
        for (int e = 1; e < 8; e++) m = fmaxf(m, acc[e]);
        float pe[8]; float s = 0.f;
        #pragma unroll
        for (int e = 0; e < 8; e++) { pe[e] = expf(acc[e] - m); s += pe[e]; }
        float inv = 1.f / s;
        #pragma unroll
        for (int e = 0; e < 8; e++) atomicAdd(&pl[e], pe[e] * inv);
    }
    __syncthreads();
    if (tid < 8) atomicAdd(&psum[tid], pl[tid]);
}

// ---------------- prefix: 128-aligned expert offsets ----------------
__global__ void k_prefix(const int* __restrict__ cnt, int* __restrict__ cur,
                         int* __restrict__ offs) {
    if (threadIdx.x == 0 && blockIdx.x == 0) {
        int off = 0;
        for (int e = 0; e < 8; e++) {
            offs[e] = off; cur[e] = off;
            off += (cnt[e] + 127) & ~127;
        }
        offs[8] = off;
        offs[9] = RC;
    }
}

// ---------------- scatter tokens into slots ----------------
__global__ void k_scatter(const int* __restrict__ topi, const float* __restrict__ topw,
                          int* __restrict__ cur, const int* __restrict__ offs,
                          int* __restrict__ stok, float* __restrict__ sw) {
    int t = blockIdx.x * 256 + threadIdx.x;
    if (t >= TK) return;
    #pragma unroll
    for (int s = 0; s < 2; s++) {
        int e = topi[t*2 + s];
        int pos = atomicAdd(&cur[e], 1);
        stok[pos] = t;
        sw[pos] = topw[t*2 + s];
    }
    int base = offs[8];
    stok[base + t] = t;
    sw[base + t] = 1.0f;
}

// ---------------- ffn1: fused gate+up GEMM + SwiGLU -> h (f16) ----------------
// n-fastest grid: blockIdx.x = n-tile, blockIdx.y = M-tile (L2: A-tile shared
// across 22 n-blocks; consecutive M-tiles same expert -> B re-reads hit cache)
__global__ __launch_bounds__(256, 2) void k_ffn1(
    const f16* __restrict__ xb, const f16* __restrict__ wgt,
    const f16* __restrict__ wut, const f16* __restrict__ sgt,
    const f16* __restrict__ sut, const int* __restrict__ offs,
    const int* __restrict__ cnt, const int* __restrict__ stok,
    f16* __restrict__ hbuf)
{
    __shared__ f16 As[128*32];
    __shared__ f16 Bg[128*32];
    __shared__ f16 Bu[128*32];

    const int n0 = blockIdx.x * 128;
    const int m0 = blockIdx.y * 128;
    int g = 0;
    while (g < 8 && m0 >= offs[g+1]) g++;
    if (m0 >= offs[8] + TK) return;
    if (g < 8 && (m0 - offs[g]) >= cnt[g]) return;

    const f16* __restrict__ Wg = (g < 8) ? wgt + (size_t)g * HP * CD : sgt;
    const f16* __restrict__ Wu = (g < 8) ? wut + (size_t)g * HP * CD : sut;

    const int tid = threadIdx.x;
    const int lane = tid & 63;
    const int w = tid >> 6;
    const int r0  = w * 32 + (lane >> 2);
    const int kof = (lane & 3) * 8;
    const f16* pa0 = xb + (size_t)stok[m0 + r0]      * CD + kof;
    const f16* pa1 = xb + (size_t)stok[m0 + r0 + 16] * CD + kof;
    const f16* pg0 = Wg + (size_t)(n0 + r0)      * CD + kof;
    const f16* pg1 = Wg + (size_t)(n0 + r0 + 16) * CD + kof;
    const f16* pu0 = Wu + (size_t)(n0 + r0)      * CD + kof;
    const f16* pu1 = Wu + (size_t)(n0 + r0 + 16) * CD + kof;
    f16* const lA = As + w * 1024;
    f16* const lG = Bg + w * 1024;
    f16* const lU = Bu + w * 1024;

    f32x4 accg[4][4], accu[4][4];
    #pragma unroll
    for (int i = 0; i < 4; i++)
        #pragma unroll
        for (int j = 0; j < 4; j++)
            #pragma unroll
            for (int r = 0; r < 4; r++) { accg[i][j][r] = 0.f; accu[i][j][r] = 0.f; }

    const int wm = (w >> 1) * 64;
    const int wn = (w & 1) * 64;
    const int fm = lane & 15;
    const int fq = lane >> 4;

    for (int k0 = 0; k0 < CD; k0 += 32) {
        GLDS16(lA,       pa0 + k0);
        GLDS16(lA + 512, pa1 + k0);
        GLDS16(lG,       pg0 + k0);
        GLDS16(lG + 512, pg1 + k0);
        GLDS16(lU,       pu0 + k0);
        GLDS16(lU + 512, pu1 + k0);
        __syncthreads();
        f16x8 af[4];
        #pragma unroll
        for (int mi = 0; mi < 4; mi++)
            af[mi] = *(const f16x8*)&As[(wm + mi*16 + fm) * 32 + fq * 8];
        #pragma unroll
        for (int ni = 0; ni < 4; ni++) {
            f16x8 bgf = *(const f16x8*)&Bg[(wn + ni*16 + fm) * 32 + fq * 8];
            f16x8 buf = *(const f16x8*)&Bu[(wn + ni*16 + fm) * 32 + fq * 8];
            #pragma unroll
            for (int mi = 0; mi < 4; mi++) {
                accg[mi][ni] = __builtin_amdgcn_mfma_f32_16x16x32_f16(af[mi], bgf, accg[mi][ni], 0, 0, 0);
                accu[mi][ni] = __builtin_amdgcn_mfma_f32_16x16x32_f16(af[mi], buf, accu[mi][ni], 0, 0, 0);
            }
        }
        __syncthreads();
    }

    #pragma unroll
    for (int mi = 0; mi < 4; mi++) {
        #pragma unroll
        for (int ni = 0; ni < 4; ni++) {
            #pragma unroll
            for (int r = 0; r < 4; r++) {
                int row = m0 + wm + mi*16 + fq*4 + r;
                int col = n0 + wn + ni*16 + fm;
                float gv = accg[mi][ni][r];
                float uv = accu[mi][ni][r];
                float hv = gv / (1.f + __expf(-gv)) * uv;
                hbuf[(size_t)row * HP + col] = (f16)hv;
            }
        }
    }
}

// ---------------- ffn2: down GEMM + weighted scatter-add ----------------
__global__ __launch_bounds__(256, 2) void k_ffn2(
    const f16* __restrict__ hbuf, const f16* __restrict__ wdt,
    const f16* __restrict__ sdt, const int* __restrict__ offs,
    const int* __restrict__ cnt, const int* __restrict__ stok,
    const float* __restrict__ sw, float* __restrict__ out)
{
    __shared__ f16 As[128*32];
    __shared__ f16 Bs[128*32];

    const int n0 = blockIdx.x * 128;
    const int m0 = blockIdx.y * 128;
    int g = 0;
    while (g < 8 && m0 >= offs[g+1]) g++;
    if (m0 >= offs[8] + TK) return;
    if (g < 8 && (m0 - offs[g]) >= cnt[g]) return;
    const f16* __restrict__ W = (g < 8) ? wdt + (size_t)g * CD * HP : sdt;

    const int tid = threadIdx.x;
    const int lane = tid & 63;
    const int w = tid >> 6;
    const int r0  = w * 32 + (lane >> 2);
    const int kof = (lane & 3) * 8;
    const f16* pa0 = hbuf + (size_t)(m0 + r0)      * HP + kof;
    const f16* pa1 = hbuf + (size_t)(m0 + r0 + 16) * HP + kof;
    const f16* pb0 = W + (size_t)(n0 + r0)      * HP + kof;
    const f16* pb1 = W + (size_t)(n0 + r0 + 16) * HP + kof;
    f16* const lA = As + w * 1024;
    f16* const lB = Bs + w * 1024;

    f32x4 acc[4][4];
    #pragma unroll
    for (int i = 0; i < 4; i++)
        #pragma unroll
        for (int j = 0; j < 4; j++)
            #pragma unroll
            for (int r = 0; r < 4; r++) acc[i][j][r] = 0.f;

    const int wm = (w >> 1) * 64;
    const int wn = (w & 1) * 64;
    const int fm = lane & 15;
    const int fq = lane >> 4;

    for (int k0 = 0; k0 < HP; k0 += 32) {
        GLDS16(lA,       pa0 + k0);
        GLDS16(lA + 512, pa1 + k0);
        GLDS16(lB,       pb0 + k0);
        GLDS16(lB + 512, pb1 + k0);
        __syncthreads();
        f16x8 af[4];
        #pragma unroll
        for (int mi = 0; mi < 4; mi++)
            af[mi] = *(const f16x8*)&As[(wm + mi*16 + fm) * 32 + fq * 8];
        #pragma unroll
        for (int ni = 0; ni < 4; ni++) {
            f16x8 bfr = *(const f16x8*)&Bs[(wn + ni*16 + fm) * 32 + fq * 8];
            #pragma unroll
            for (int mi = 0; mi < 4; mi++)
                acc[mi][ni] = __builtin_amdgcn_mfma_f32_16x16x32_f16(af[mi], bfr, acc[mi][ni], 0, 0, 0);
        }
        __syncthreads();
    }

    #pragma unroll
    for (int mi = 0; mi < 4; mi++) {
        #pragma unroll
        for (int r = 0; r < 4; r++) {
            int row = m0 + wm + mi*16 + fq*4 + r;
            int tok = stok[row];
            float wgt = sw[row];
            if (wgt != 0.f) {
                #pragma unroll
                for (int ni = 0; ni < 4; ni++) {
                    int col = n0 + wn + ni*16 + fm;
                    atomicAdd(&out[(size_t)tok * CD + col], wgt * acc[mi][ni][r]);
                }
            }
        }
    }
}

// ---------------- aux loss ----------------
__global__ void k_aux(const int* __restrict__ cnt, const float* __restrict__ psum,
                      float* __restrict__ out_aux) {
    if (threadIdx.x == 0 && blockIdx.x == 0) {
        float a = 0.f;
        for (int e = 0; e < 8; e++) {
            float f = (float)cnt[e] / ((float)TK * 2.f);
            float p = psum[e] / (float)TK;
            a += f * p;
        }
        out_aux[0] = 8.f * a;
    }
}

extern "C" void kernel_launch(void* const* d_in, const int* in_sizes, int n_in,
                              void* d_out, int out_size, void* d_ws, size_t ws_size,
                              hipStream_t stream) {
    const float* x  = (const float*)d_in[0];
    const float* rw = (const float*)d_in[1];
    const float* wg = (const float*)d_in[2];
    const float* wu = (const float*)d_in[3];
    const float* wd = (const float*)d_in[4];
    const float* sg = (const float*)d_in[5];
    const float* su = (const float*)d_in[6];
    const float* sd = (const float*)d_in[7];
    float* out = (float*)d_out;

    char* ws = (char*)d_ws;
    f16* xb   = (f16*)(ws + WS_XB);
    f16* hbuf = (f16*)(ws + WS_H);
    f16* wgt  = (f16*)(ws + WS_WGT);
    f16* wut  = (f16*)(ws + WS_WUT);
    f16* wdt  = (f16*)(ws + WS_WDT);
    f16* sgt  = (f16*)(ws + WS_SGT);
    f16* sut  = (f16*)(ws + WS_SUT);
    f16* sdt  = (f16*)(ws + WS_SDT);
    char* ct  = ws + WS_CT;
    int*   stok = (int*)  (ct + CT_STOK);
    float* swt  = (float*)(ct + CT_SW);
    int*   topi = (int*)  (ct + CT_TI);
    float* topw = (float*)(ct + CT_TW);
    int*   cnt  = (int*)  (ct + CT_CNT);
    float* psum = (float*)(ct + CT_PS);
    int*   cur  = (int*)  (ct + CT_CUR);
    int*   offs = (int*)  (ct + CT_OFF);

    hipMemsetAsync(d_out, 0, (size_t)(TK * CD + 1) * 4, stream);
    hipMemsetAsync(ct, 0, CT_SIZE, stream);

    k_xb<<<dim3(TK * CD / 1024), dim3(256), 0, stream>>>(x, xb);
    k_router<<<dim3(TK / 4), dim3(256), 0, stream>>>(x, rw, topi, topw, cnt, psum);
    k_prefix<<<dim3(1), dim3(64), 0, stream>>>(cnt, cur, offs);
    k_scatter<<<dim3(TK / 256), dim3(256), 0, stream>>>(topi, topw, cur, offs, stok, swt);

    // weight convert+transpose: [R][Cc] fp32 -> [Cp][Rp] f16 (0-padded)
    k_tr<<<dim3(HP/128, CD/64, 8), dim3(256), 0, stream>>>(wg, wgt, CD, HD, CD, HP, (size_t)CD*HD, (size_t)HP*CD);
    k_tr<<<dim3(HP/128, CD/64, 8), dim3(256), 0, stream>>>(wu, wut, CD, HD, CD, HP, (size_t)CD*HD, (size_t)HP*CD);
    k_tr<<<dim3(CD/128, HP/64, 8), dim3(256), 0, stream>>>(wd, wdt, HD, CD, HP, CD, (size_t)HD*CD, (size_t)CD*HP);
    k_tr<<<dim3(HP/128, CD/64, 1), dim3(256), 0, stream>>>(sg, sgt, CD, HD, CD, HP, 0, 0);
    k_tr<<<dim3(HP/128, CD/64, 1), dim3(256), 0, stream>>>(su, sut, CD, HD, CD, HP, 0, 0);
    k_tr<<<dim3(CD/128, HP/64, 1), dim3(256), 0, stream>>>(sd, sdt, HD, CD, HP, CD, 0, 0);

    k_ffn1<<<dim3(HP/128, MT), dim3(256), 0, stream>>>(xb, wgt, wut, sgt, sut, offs, cnt, stok, hbuf);
    k_ffn2<<<dim3(CD/128, MT), dim3(256), 0, stream>>>(hbuf, wdt, sdt, offs, cnt, stok, swt, out);
    k_aux<<<dim3(1), dim3(64), 0, stream>>>(cnt, psum, out + (size_t)TK * CD);
}

// Round 4
// 797.537 us; speedup vs baseline: 1.8136x; 1.0443x over previous
//
#include <hip/hip_runtime.h>

typedef _Float16 f16;
typedef _Float16 f16x4 __attribute__((ext_vector_type(4)));
typedef _Float16 f16x8 __attribute__((ext_vector_type(8)));
typedef float f32x4 __attribute__((ext_vector_type(4)));

#define TK 4096      // tokens
#define CD 1024      // C
#define HD 2736      // H
#define HP 2816      // H padded to 22*128
#define MT 104       // max M tiles: sum ceil(cnt_e/128) <= 72, + 32 shared
#define RC 13312     // MT*128 slot rows

// async global->LDS, 16B per lane, lds dest = wave-uniform base + lane*16
#define GLDS16(ldsp, gp) __builtin_amdgcn_global_load_lds( \
    (const __attribute__((address_space(1))) unsigned int*)(gp), \
    (__attribute__((address_space(3))) unsigned int*)(ldsp), 16, 0, 0)

// ---- workspace layout (bytes) ----
static constexpr size_t WS_XB  = 0;                               // f16 x (8.4 MB)
static constexpr size_t WS_H   = WS_XB  + (size_t)TK*CD*2;        // f16 h (75 MB)
static constexpr size_t WS_WGT = WS_H   + (size_t)RC*HP*2;        // f16 [8][HP][CD]
static constexpr size_t WS_WUT = WS_WGT + (size_t)8*HP*CD*2;
static constexpr size_t WS_WDT = WS_WUT + (size_t)8*HP*CD*2;      // f16 [8][CD][HP]
static constexpr size_t WS_SGT = WS_WDT + (size_t)8*CD*HP*2;      // f16 [HP][CD]
static constexpr size_t WS_SUT = WS_SGT + (size_t)HP*CD*2;
static constexpr size_t WS_SDT = WS_SUT + (size_t)HP*CD*2;        // f16 [CD][HP]
static constexpr size_t WS_CT  = WS_SDT + (size_t)CD*HP*2;        // control block
// obuf (fp32 [RC][CD], 54.5 MB) aliases wgt+wut (92 MB) — dead after ffn1
static constexpr size_t WS_OBUF = WS_WGT;
static constexpr size_t CT_STOK = 0;                         // int[RC]
static constexpr size_t CT_SW   = CT_STOK + (size_t)RC*4;    // float[RC]
static constexpr size_t CT_TI   = CT_SW   + (size_t)RC*4;    // int[TK*2]
static constexpr size_t CT_TW   = CT_TI   + (size_t)TK*2*4;  // float[TK*2]
static constexpr size_t CT_ISL  = CT_TW   + (size_t)TK*2*4;  // int[TK*2] inverse slot map
static constexpr size_t CT_CNT  = CT_ISL  + (size_t)TK*2*4;  // int[8]
static constexpr size_t CT_PS   = CT_CNT  + 32;              // float[8]
static constexpr size_t CT_CUR  = CT_PS   + 32;              // int[8]
static constexpr size_t CT_OFF  = CT_CUR  + 32;              // int[10]
static constexpr size_t CT_SIZE = CT_OFF  + 64;

// ---------------- weight convert+transpose, register-only ----------------
// src fp32 [R][Cc] -> dst f16 [Cp][Rp], zero-padded. Block covers dst
// 128 rows (cc) x 64 cols (rr). Lane: 8 coalesced float4 loads, register
// transpose, 4 f16x8 stores. grid.z multiplexes experts (+1 shared slab).
__global__ __launch_bounds__(256) void k_tr(
    const float* __restrict__ srcMain, f16* __restrict__ dstMain,
    const float* __restrict__ srcSh,   f16* __restrict__ dstSh,
    int R, int Cc, int Rp, int Cp, int nMain,
    size_t sstride, size_t dstride) {
    const float* src; f16* dst;
    if ((int)blockIdx.z < nMain) {
        src = srcMain + (size_t)blockIdx.z * sstride;
        dst = dstMain + (size_t)blockIdx.z * dstride;
    } else {
        src = srcSh; dst = dstSh;
    }
    const int tid = threadIdx.x;
    const int l = tid & 63, w = tid >> 6;
    const int cc0 = blockIdx.x * 128 + w * 32 + (l >> 3) * 4;   // dst row = src col
    const int rr0 = blockIdx.y * 64 + (l & 7) * 8;              // dst col = src row
    float4 v[8];
    #pragma unroll
    for (int e = 0; e < 8; e++) {
        int gr = rr0 + e;
        if (gr < R && cc0 + 3 < Cc) {
            v[e] = *(const float4*)(src + (size_t)gr * Cc + cc0);
        } else {
            float* ve = (float*)&v[e];
            #pragma unroll
            for (int c = 0; c < 4; c++)
                ve[c] = (gr < R && cc0 + c < Cc) ? src[(size_t)gr * Cc + cc0 + c] : 0.f;
        }
    }
    #pragma unroll
    for (int c = 0; c < 4; c++) {
        const float* vp = (const float*)v;
        f16x8 o = { (f16)vp[0*4+c], (f16)vp[1*4+c], (f16)vp[2*4+c], (f16)vp[3*4+c],
                    (f16)vp[4*4+c], (f16)vp[5*4+c], (f16)vp[6*4+c], (f16)vp[7*4+c] };
        *(f16x8*)(dst + (size_t)(cc0 + c) * Rp + rr0) = o;
    }
}

// ---------------- router (fp32) + x->f16 cast fused ----------------
__global__ void k_router(const float* __restrict__ x, const float* __restrict__ rw,
                         f16* __restrict__ xb,
                         int* __restrict__ topi, float* __restrict__ topw,
                         int* __restrict__ cnt, float* __restrict__ psum) {
    __shared__ float pl[8];
    int tid = threadIdx.x;
    if (tid < 8) pl[tid] = 0.f;
    __syncthreads();
    int wave = tid >> 6, lane = tid & 63;
    int t = blockIdx.x * 4 + wave;
    float acc[8];
    #pragma unroll
    for (int e = 0; e < 8; e++) acc[e] = 0.f;
    const float* xr = x + (size_t)t * CD;
    f16* xbr = xb + (size_t)t * CD;
    for (int i = 0; i < CD / 64; i++) {
        int c = lane + i * 64;
        float xv = xr[c];
        xbr[c] = (f16)xv;                       // fused cast
        const float* wr = rw + c * 8;
        #pragma unroll
        for (int e = 0; e < 8; e++) acc[e] = fmaf(xv, wr[e], acc[e]);
    }
    #pragma unroll
    for (int e = 0; e < 8; e++) {
        #pragma unroll
        for (int off = 32; off; off >>= 1) acc[e] += __shfl_xor(acc[e], off);
    }
    if (lane == 0) {
        float v1 = -1e30f; int i1 = 0;
        #pragma unroll
        for (int e = 0; e < 8; e++) if (acc[e] > v1) { v1 = acc[e]; i1 = e; }
        float v2 = -1e30f; int i2 = (i1 == 0) ? 1 : 0;
        #pragma unroll
        for (int e = 0; e < 8; e++) if (e != i1 && acc[e] > v2) { v2 = acc[e]; i2 = e; }
        float b = expf(v2 - v1);
        float w1 = 1.f / (1.f + b);
        topi[t*2] = i1; topi[t*2+1] = i2;
        topw[t*2] = w1; topw[t*2+1] = b * w1;
        atomicAdd(&cnt[i1], 1);
        atomicAdd(&cnt[i2], 1);
        float m = acc[0];
        #pragma unroll
        for (int e = 1; e < 8; e++) m = fmaxf(m, acc[e]);
        float pe[8]; float s = 0.f;
        #pragma unroll
        for (int e = 0; e < 8; e++) { pe[e] = expf(acc[e] - m); s += pe[e]; }
        float inv = 1.f / s;
        #pragma unroll
        for (int e = 0; e < 8; e++) atomicAdd(&pl[e], pe[e] * inv);
    }
    __syncthreads();
    if (tid < 8) atomicAdd(&psum[tid], pl[tid]);
}

// ---------------- prefix: 128-aligned expert offsets ----------------
__global__ void k_prefix(const int* __restrict__ cnt, int* __restrict__ cur,
                         int* __restrict__ offs) {
    if (threadIdx.x == 0 && blockIdx.x == 0) {
        int off = 0;
        for (int e = 0; e < 8; e++) {
            offs[e] = off; cur[e] = off;
            off += (cnt[e] + 127) & ~127;
        }
        offs[8] = off;
        offs[9] = RC;
    }
}

// ---------------- scatter tokens into slots (+ inverse map) ----------------
__global__ void k_scatter(const int* __restrict__ topi, const float* __restrict__ topw,
                          int* __restrict__ cur, const int* __restrict__ offs,
                          int* __restrict__ stok, float* __restrict__ sw,
                          int* __restrict__ islot) {
    int t = blockIdx.x * 256 + threadIdx.x;
    if (t >= TK) return;
    #pragma unroll
    for (int s = 0; s < 2; s++) {
        int e = topi[t*2 + s];
        int pos = atomicAdd(&cur[e], 1);
        stok[pos] = t;
        sw[pos] = topw[t*2 + s];
        islot[t*2 + s] = pos;
    }
    int base = offs[8];
    stok[base + t] = t;
    sw[base + t] = 1.0f;
}

// ---------------- ffn1: fused gate+up GEMM + SwiGLU -> h (f16) ----------------
__global__ __launch_bounds__(256, 2) void k_ffn1(
    const f16* __restrict__ xb, const f16* __restrict__ wgt,
    const f16* __restrict__ wut, const f16* __restrict__ sgt,
    const f16* __restrict__ sut, const int* __restrict__ offs,
    const int* __restrict__ cnt, const int* __restrict__ stok,
    f16* __restrict__ hbuf)
{
    __shared__ f16 As[128*32];
    __shared__ f16 Bg[128*32];
    __shared__ f16 Bu[128*32];

    const int n0 = blockIdx.x * 128;
    const int m0 = blockIdx.y * 128;
    int g = 0;
    while (g < 8 && m0 >= offs[g+1]) g++;
    if (m0 >= offs[8] + TK) return;
    if (g < 8 && (m0 - offs[g]) >= cnt[g]) return;

    const f16* __restrict__ Wg = (g < 8) ? wgt + (size_t)g * HP * CD : sgt;
    const f16* __restrict__ Wu = (g < 8) ? wut + (size_t)g * HP * CD : sut;

    const int tid = threadIdx.x;
    const int lane = tid & 63;
    const int w = tid >> 6;
    const int r0  = w * 32 + (lane >> 2);
    const int kof = (lane & 3) * 8;
    const f16* pa0 = xb + (size_t)stok[m0 + r0]      * CD + kof;
    const f16* pa1 = xb + (size_t)stok[m0 + r0 + 16] * CD + kof;
    const f16* pg0 = Wg + (size_t)(n0 + r0)      * CD + kof;
    const f16* pg1 = Wg + (size_t)(n0 + r0 + 16) * CD + kof;
    const f16* pu0 = Wu + (size_t)(n0 + r0)      * CD + kof;
    const f16* pu1 = Wu + (size_t)(n0 + r0 + 16) * CD + kof;
    f16* const lA = As + w * 1024;
    f16* const lG = Bg + w * 1024;
    f16* const lU = Bu + w * 1024;

    f32x4 accg[4][4], accu[4][4];
    #pragma unroll
    for (int i = 0; i < 4; i++)
        #pragma unroll
        for (int j = 0; j < 4; j++)
            #pragma unroll
            for (int r = 0; r < 4; r++) { accg[i][j][r] = 0.f; accu[i][j][r] = 0.f; }

    const int wm = (w >> 1) * 64;
    const int wn = (w & 1) * 64;
    const int fm = lane & 15;
    const int fq = lane >> 4;

    for (int k0 = 0; k0 < CD; k0 += 32) {
        GLDS16(lA,       pa0 + k0);
        GLDS16(lA + 512, pa1 + k0);
        GLDS16(lG,       pg0 + k0);
        GLDS16(lG + 512, pg1 + k0);
        GLDS16(lU,       pu0 + k0);
        GLDS16(lU + 512, pu1 + k0);
        __syncthreads();
        f16x8 af[4];
        #pragma unroll
        for (int mi = 0; mi < 4; mi++)
            af[mi] = *(const f16x8*)&As[(wm + mi*16 + fm) * 32 + fq * 8];
        #pragma unroll
        for (int ni = 0; ni < 4; ni++) {
            f16x8 bgf = *(const f16x8*)&Bg[(wn + ni*16 + fm) * 32 + fq * 8];
            f16x8 buf = *(const f16x8*)&Bu[(wn + ni*16 + fm) * 32 + fq * 8];
            #pragma unroll
            for (int mi = 0; mi < 4; mi++) {
                accg[mi][ni] = __builtin_amdgcn_mfma_f32_16x16x32_f16(af[mi], bgf, accg[mi][ni], 0, 0, 0);
                accu[mi][ni] = __builtin_amdgcn_mfma_f32_16x16x32_f16(af[mi], buf, accu[mi][ni], 0, 0, 0);
            }
        }
        __syncthreads();
    }

    #pragma unroll
    for (int mi = 0; mi < 4; mi++) {
        #pragma unroll
        for (int ni = 0; ni < 4; ni++) {
            #pragma unroll
            for (int r = 0; r < 4; r++) {
                int row = m0 + wm + mi*16 + fq*4 + r;
                int col = n0 + wn + ni*16 + fm;
                float gv = accg[mi][ni][r];
                float uv = accu[mi][ni][r];
                float hv = gv / (1.f + __expf(-gv)) * uv;
                hbuf[(size_t)row * HP + col] = (f16)hv;
            }
        }
    }
}

// ---------------- ffn2: down GEMM -> per-slot obuf (no atomics) ----------------
__global__ __launch_bounds__(256, 2) void k_ffn2(
    const f16* __restrict__ hbuf, const f16* __restrict__ wdt,
    const f16* __restrict__ sdt, const int* __restrict__ offs,
    const int* __restrict__ cnt, float* __restrict__ obuf)
{
    __shared__ f16 As[128*32];
    __shared__ f16 Bs[128*32];

    const int n0 = blockIdx.x * 128;
    const int m0 = blockIdx.y * 128;
    int g = 0;
    while (g < 8 && m0 >= offs[g+1]) g++;
    if (m0 >= offs[8] + TK) return;
    if (g < 8 && (m0 - offs[g]) >= cnt[g]) return;
    const f16* __restrict__ W = (g < 8) ? wdt + (size_t)g * CD * HP : sdt;

    const int tid = threadIdx.x;
    const int lane = tid & 63;
    const int w = tid >> 6;
    const int r0  = w * 32 + (lane >> 2);
    const int kof = (lane & 3) * 8;
    const f16* pa0 = hbuf + (size_t)(m0 + r0)      * HP + kof;
    const f16* pa1 = hbuf + (size_t)(m0 + r0 + 16) * HP + kof;
    const f16* pb0 = W + (size_t)(n0 + r0)      * HP + kof;
    const f16* pb1 = W + (size_t)(n0 + r0 + 16) * HP + kof;
    f16* const lA = As + w * 1024;
    f16* const lB = Bs + w * 1024;

    f32x4 acc[4][4];
    #pragma unroll
    for (int i = 0; i < 4; i++)
        #pragma unroll
        for (int j = 0; j < 4; j++)
            #pragma unroll
            for (int r = 0; r < 4; r++) acc[i][j][r] = 0.f;

    const int wm = (w >> 1) * 64;
    const int wn = (w & 1) * 64;
    const int fm = lane & 15;
    const int fq = lane >> 4;

    for (int k0 = 0; k0 < HP; k0 += 32) {
        GLDS16(lA,       pa0 + k0);
        GLDS16(lA + 512, pa1 + k0);
        GLDS16(lB,       pb0 + k0);
        GLDS16(lB + 512, pb1 + k0);
        __syncthreads();
        f16x8 af[4];
        #pragma unroll
        for (int mi = 0; mi < 4; mi++)
            af[mi] = *(const f16x8*)&As[(wm + mi*16 + fm) * 32 + fq * 8];
        #pragma unroll
        for (int ni = 0; ni < 4; ni++) {
            f16x8 bfr = *(const f16x8*)&Bs[(wn + ni*16 + fm) * 32 + fq * 8];
            #pragma unroll
            for (int mi = 0; mi < 4; mi++)
                acc[mi][ni] = __builtin_amdgcn_mfma_f32_16x16x32_f16(af[mi], bfr, acc[mi][ni], 0, 0, 0);
        }
        __syncthreads();
    }

    #pragma unroll
    for (int mi = 0; mi < 4; mi++) {
        #pragma unroll
        for (int r = 0; r < 4; r++) {
            int row = m0 + wm + mi*16 + fq*4 + r;
            #pragma unroll
            for (int ni = 0; ni < 4; ni++) {
                int col = n0 + wn + ni*16 + fm;
                obuf[(size_t)row * CD + col] = acc[mi][ni][r];
            }
        }
    }
}

// ---------------- combine: out[t] = w0*o[s0] + w1*o[s1] + o[shared] ----------------
__global__ __launch_bounds__(256) void k_comb(
    const float* __restrict__ obuf, const int* __restrict__ islot,
    const float* __restrict__ topw, const int* __restrict__ offs,
    float* __restrict__ out)
{
    const int t = blockIdx.x;
    const int c = threadIdx.x * 4;
    const int s0 = islot[t*2], s1 = islot[t*2+1];
    const float w0 = topw[t*2], w1 = topw[t*2+1];
    const int sh = offs[8] + t;
    float4 a = *(const float4*)(obuf + (size_t)s0 * CD + c);
    float4 b = *(const float4*)(obuf + (size_t)s1 * CD + c);
    float4 s = *(const float4*)(obuf + (size_t)sh * CD + c);
    float4 o;
    o.x = fmaf(w0, a.x, fmaf(w1, b.x, s.x));
    o.y = fmaf(w0, a.y, fmaf(w1, b.y, s.y));
    o.z = fmaf(w0, a.z, fmaf(w1, b.z, s.z));
    o.w = fmaf(w0, a.w, fmaf(w1, b.w, s.w));
    *(float4*)(out + (size_t)t * CD + c) = o;
}

// ---------------- aux loss ----------------
__global__ void k_aux(const int* __restrict__ cnt, const float* __restrict__ psum,
                      float* __restrict__ out_aux) {
    if (threadIdx.x == 0 && blockIdx.x == 0) {
        float a = 0.f;
        for (int e = 0; e < 8; e++) {
            float f = (float)cnt[e] / ((float)TK * 2.f);
            float p = psum[e] / (float)TK;
            a += f * p;
        }
        out_aux[0] = 8.f * a;
    }
}

extern "C" void kernel_launch(void* const* d_in, const int* in_sizes, int n_in,
                              void* d_out, int out_size, void* d_ws, size_t ws_size,
                              hipStream_t stream) {
    const float* x  = (const float*)d_in[0];
    const float* rw = (const float*)d_in[1];
    const float* wg = (const float*)d_in[2];
    const float* wu = (const float*)d_in[3];
    const float* wd = (const float*)d_in[4];
    const float* sg = (const float*)d_in[5];
    const float* su = (const float*)d_in[6];
    const float* sd = (const float*)d_in[7];
    float* out = (float*)d_out;

    char* ws = (char*)d_ws;
    f16* xb   = (f16*)(ws + WS_XB);
    f16* hbuf = (f16*)(ws + WS_H);
    f16* wgt  = (f16*)(ws + WS_WGT);
    f16* wut  = (f16*)(ws + WS_WUT);
    f16* wdt  = (f16*)(ws + WS_WDT);
    f16* sgt  = (f16*)(ws + WS_SGT);
    f16* sut  = (f16*)(ws + WS_SUT);
    f16* sdt  = (f16*)(ws + WS_SDT);
    float* obuf = (float*)(ws + WS_OBUF);
    char* ct  = ws + WS_CT;
    int*   stok = (int*)  (ct + CT_STOK);
    float* swt  = (float*)(ct + CT_SW);
    int*   topi = (int*)  (ct + CT_TI);
    float* topw = (float*)(ct + CT_TW);
    int*   isl  = (int*)  (ct + CT_ISL);
    int*   cnt  = (int*)  (ct + CT_CNT);
    float* psum = (float*)(ct + CT_PS);
    int*   cur  = (int*)  (ct + CT_CUR);
    int*   offs = (int*)  (ct + CT_OFF);

    hipMemsetAsync(ct, 0, CT_SIZE, stream);

    k_router<<<dim3(TK / 4), dim3(256), 0, stream>>>(x, rw, xb, topi, topw, cnt, psum);
    k_prefix<<<dim3(1), dim3(64), 0, stream>>>(cnt, cur, offs);
    k_scatter<<<dim3(TK / 256), dim3(256), 0, stream>>>(topi, topw, cur, offs, stok, swt, isl);

    // weight convert+transpose, grid.z = 8 experts + 1 shared slab
    k_tr<<<dim3(HP/128, CD/64, 9), dim3(256), 0, stream>>>(
        wg, wgt, sg, sgt, CD, HD, CD, HP, 8, (size_t)CD*HD, (size_t)HP*CD);
    k_tr<<<dim3(HP/128, CD/64, 9), dim3(256), 0, stream>>>(
        wu, wut, su, sut, CD, HD, CD, HP, 8, (size_t)CD*HD, (size_t)HP*CD);
    k_tr<<<dim3(CD/128, HP/64, 9), dim3(256), 0, stream>>>(
        wd, wdt, sd, sdt, HD, CD, HP, CD, 8, (size_t)HD*CD, (size_t)CD*HP);

    k_ffn1<<<dim3(HP/128, MT), dim3(256), 0, stream>>>(xb, wgt, wut, sgt, sut, offs, cnt, stok, hbuf);
    k_ffn2<<<dim3(CD/128, MT), dim3(256), 0, stream>>>(hbuf, wdt, sdt, offs, cnt, obuf);
    k_comb<<<dim3(TK), dim3(256), 0, stream>>>(obuf, isl, topw, offs, out);
    k_aux<<<dim3(1), dim3(64), 0, stream>>>(cnt, psum, out + (size_t)TK * CD);
}